// Round 1
// baseline (1560.911 us; speedup 1.0000x reference)
//
#include <hip/hip_runtime.h>
#include <hip/hip_bf16.h>

static constexpr int B_ = 4;
static constexpr int S_ = 1024;
static constexpr int D_ = 1024;
static constexpr int H_ = 16;
static constexpr int DH_ = 64;
static constexpr float SCALE = 0.125f;  // 1/sqrt(64)

__device__ __forceinline__ float sigm(float x) { return 1.0f / (1.0f + __expf(-x)); }

// ---------------------------------------------------------------------------
// QKV projection: C[4096,3072] = HS[4096,1024] @ [Wq|Wk|Wv] + bias
// scattered into q/k/v with [B,H,S,DH] layout.
// 64x64 tile, BK=32, 256 threads, 4x4 micro-tile per thread.
// A staged transposed in LDS so inner loop is two ds_read_b128 + 16 FMA.
// ---------------------------------------------------------------------------
__global__ __launch_bounds__(256) void gemm_qkv(
    const float* __restrict__ A,
    const float* __restrict__ Wq, const float* __restrict__ bq,
    const float* __restrict__ Wk, const float* __restrict__ bk,
    const float* __restrict__ Wv, const float* __restrict__ bv,
    float* __restrict__ qo, float* __restrict__ ko, float* __restrict__ vo)
{
    __shared__ float At[32][64];   // [k][m]
    __shared__ float Bs[32][64];   // [k][n]
    const int t  = threadIdx.x;
    const int bx = blockIdx.x;     // 0..47 over N=3072
    const int by = blockIdx.y;     // 0..63 over M=4096
    const int mat   = bx >> 4;     // 0=q, 1=k, 2=v
    const int ncol0 = (bx & 15) * 64;
    const float* W   = (mat == 0) ? Wq : (mat == 1) ? Wk : Wv;
    const float* bi  = (mat == 0) ? bq : (mat == 1) ? bk : bv;
    float*       out = (mat == 0) ? qo : (mat == 1) ? ko : vo;

    const int tx = t & 15, ty = t >> 4;
    const int ar = t >> 3, ac = (t & 7) << 2;   // A tile: 64 rows x 32 k
    const int br = t >> 4, bc = (t & 15) << 2;  // B tile: 32 k x 64 cols

    float acc[4][4] = {};
    for (int k0 = 0; k0 < D_; k0 += 32) {
        float4 a0 = *(const float4*)(A + (size_t)(by * 64 + ar) * D_ + k0 + ac);
        float4 a1 = *(const float4*)(A + (size_t)(by * 64 + ar + 32) * D_ + k0 + ac);
        float4 b0 = *(const float4*)(W + (size_t)(k0 + br) * D_ + ncol0 + bc);
        float4 b1 = *(const float4*)(W + (size_t)(k0 + br + 16) * D_ + ncol0 + bc);
        At[ac + 0][ar] = a0.x; At[ac + 1][ar] = a0.y;
        At[ac + 2][ar] = a0.z; At[ac + 3][ar] = a0.w;
        At[ac + 0][ar + 32] = a1.x; At[ac + 1][ar + 32] = a1.y;
        At[ac + 2][ar + 32] = a1.z; At[ac + 3][ar + 32] = a1.w;
        *(float4*)(&Bs[br][bc])      = b0;
        *(float4*)(&Bs[br + 16][bc]) = b1;
        __syncthreads();
        #pragma unroll
        for (int kk = 0; kk < 32; ++kk) {
            float4 avv = *(const float4*)(&At[kk][ty * 4]);
            float4 bvv = *(const float4*)(&Bs[kk][tx * 4]);
            const float* av = reinterpret_cast<const float*>(&avv);
            const float* bv = reinterpret_cast<const float*>(&bvv);
            #pragma unroll
            for (int i = 0; i < 4; ++i)
                #pragma unroll
                for (int j = 0; j < 4; ++j)
                    acc[i][j] = fmaf(av[i], bv[j], acc[i][j]);
        }
        __syncthreads();
    }
    const int hh = ncol0 >> 6;  // whole 64-wide tile lies in one head
    #pragma unroll
    for (int i = 0; i < 4; ++i) {
        int m  = by * 64 + ty * 4 + i;
        int bb = m >> 10, ss = m & (S_ - 1);
        float* dst = out + ((size_t)(bb * H_ + hh) * S_ + ss) * DH_ + tx * 4;
        float4 ov;
        ((float*)&ov)[0] = acc[i][0] + bi[ncol0 + tx * 4 + 0];
        ((float*)&ov)[1] = acc[i][1] + bi[ncol0 + tx * 4 + 1];
        ((float*)&ov)[2] = acc[i][2] + bi[ncol0 + tx * 4 + 2];
        ((float*)&ov)[3] = acc[i][3] + bi[ncol0 + tx * 4 + 3];
        *(float4*)dst = ov;
    }
}

// ---------------------------------------------------------------------------
// cq/ck projection: [4096,1024] @ [1024,64] + bias. grid (2, 64); bx=0 -> cq.
// ---------------------------------------------------------------------------
__global__ __launch_bounds__(256) void gemm_cqck(
    const float* __restrict__ A,
    const float* __restrict__ Wcq, const float* __restrict__ bcq,
    const float* __restrict__ Wck, const float* __restrict__ bck,
    float* __restrict__ cqo, float* __restrict__ cko)
{
    __shared__ float At[32][64];
    __shared__ float Bs[32][64];
    const int t  = threadIdx.x;
    const int bx = blockIdx.x;     // 0: cq, 1: ck
    const int by = blockIdx.y;     // 0..63
    const float* W   = bx ? Wck : Wcq;
    const float* bi  = bx ? bck : bcq;
    float*       out = bx ? cko : cqo;

    const int tx = t & 15, ty = t >> 4;
    const int ar = t >> 3, ac = (t & 7) << 2;
    const int br = t >> 4, bc = (t & 15) << 2;

    float acc[4][4] = {};
    for (int k0 = 0; k0 < D_; k0 += 32) {
        float4 a0 = *(const float4*)(A + (size_t)(by * 64 + ar) * D_ + k0 + ac);
        float4 a1 = *(const float4*)(A + (size_t)(by * 64 + ar + 32) * D_ + k0 + ac);
        float4 b0 = *(const float4*)(W + (size_t)(k0 + br) * DH_ + bc);
        float4 b1 = *(const float4*)(W + (size_t)(k0 + br + 16) * DH_ + bc);
        At[ac + 0][ar] = a0.x; At[ac + 1][ar] = a0.y;
        At[ac + 2][ar] = a0.z; At[ac + 3][ar] = a0.w;
        At[ac + 0][ar + 32] = a1.x; At[ac + 1][ar + 32] = a1.y;
        At[ac + 2][ar + 32] = a1.z; At[ac + 3][ar + 32] = a1.w;
        *(float4*)(&Bs[br][bc])      = b0;
        *(float4*)(&Bs[br + 16][bc]) = b1;
        __syncthreads();
        #pragma unroll
        for (int kk = 0; kk < 32; ++kk) {
            float4 avv = *(const float4*)(&At[kk][ty * 4]);
            float4 bvv = *(const float4*)(&Bs[kk][tx * 4]);
            const float* av = reinterpret_cast<const float*>(&avv);
            const float* bv = reinterpret_cast<const float*>(&bvv);
            #pragma unroll
            for (int i = 0; i < 4; ++i)
                #pragma unroll
                for (int j = 0; j < 4; ++j)
                    acc[i][j] = fmaf(av[i], bv[j], acc[i][j]);
        }
        __syncthreads();
    }
    #pragma unroll
    for (int i = 0; i < 4; ++i) {
        int m = by * 64 + ty * 4 + i;
        float4 ov;
        ((float*)&ov)[0] = acc[i][0] + bi[tx * 4 + 0];
        ((float*)&ov)[1] = acc[i][1] + bi[tx * 4 + 1];
        ((float*)&ov)[2] = acc[i][2] + bi[tx * 4 + 2];
        ((float*)&ov)[3] = acc[i][3] + bi[tx * 4 + 3];
        *(float4*)(out + (size_t)m * DH_ + tx * 4) = ov;
    }
}

// ---------------------------------------------------------------------------
// lambda_context[b,h,s] = 1 - sigm(cq.w_lqc + q.w_lqq) - sigm(ck.w_lkc + k.w_lkk)
// ---------------------------------------------------------------------------
__global__ __launch_bounds__(256) void lambda_kernel(
    const float* __restrict__ q, const float* __restrict__ k,
    const float* __restrict__ cq, const float* __restrict__ ck,
    const float* __restrict__ wlqc, const float* __restrict__ wlqq,
    const float* __restrict__ wlkc, const float* __restrict__ wlkk,
    float* __restrict__ lam)
{
    __shared__ float w[4][64];
    const int t = threadIdx.x;
    if (t < 64) { w[0][t] = wlqc[t]; w[1][t] = wlqq[t]; w[2][t] = wlkc[t]; w[3][t] = wlkk[t]; }
    __syncthreads();
    const int idx = blockIdx.x * 256 + t;       // (b*H+h)*S + s
    const int ssi = idx & (S_ - 1);
    const int bh  = idx >> 10;
    const int b   = bh >> 4;
    const float* qrow  = q  + (size_t)idx * DH_;
    const float* krow  = k  + (size_t)idx * DH_;
    const float* cqrow = cq + ((size_t)b * S_ + ssi) * DH_;
    const float* ckrow = ck + ((size_t)b * S_ + ssi) * DH_;
    float s1 = 0.f, s2 = 0.f, s3 = 0.f, s4 = 0.f;
    #pragma unroll 8
    for (int d = 0; d < DH_; ++d) {
        s1 = fmaf(cqrow[d], w[0][d], s1);
        s2 = fmaf(qrow[d],  w[1][d], s2);
        s3 = fmaf(ckrow[d], w[2][d], s3);
        s4 = fmaf(krow[d],  w[3][d], s4);
    }
    lam[idx] = 1.0f - sigm(s1 + s2) - sigm(s3 + s4);
}

// ---------------------------------------------------------------------------
// Generic K=64 score GEMM over slices: O[i,j] = (A_z[i,:] . B_z[j,:])*scale
// + mask[b,j], optional sigmoid. Used for quasi (z=b) and raw scores (z=b*H+h).
// ---------------------------------------------------------------------------
__global__ __launch_bounds__(256) void score64(
    const float* __restrict__ Abase, const float* __restrict__ Bbase,
    float* __restrict__ Obase, const float* __restrict__ mask,
    int bshift, int do_sig)
{
    __shared__ float At[64][64];   // [d][i]
    __shared__ float Bt[64][64];   // [d][j]
    const int z  = blockIdx.z;
    const int jt = blockIdx.x, it = blockIdx.y;
    const float* Am = Abase + (size_t)z * S_ * DH_;
    const float* Bm = Bbase + (size_t)z * S_ * DH_;
    float*       Om = Obase + (size_t)z * S_ * S_;
    const int b = z >> bshift;
    const int t = threadIdx.x;
    const int r = t >> 2, c0 = (t & 3) << 4;
    #pragma unroll
    for (int u = 0; u < 4; ++u) {
        float4 av = *(const float4*)(Am + (size_t)(it * 64 + r) * DH_ + c0 + u * 4);
        float4 bv = *(const float4*)(Bm + (size_t)(jt * 64 + r) * DH_ + c0 + u * 4);
        At[c0 + u * 4 + 0][r] = av.x; At[c0 + u * 4 + 1][r] = av.y;
        At[c0 + u * 4 + 2][r] = av.z; At[c0 + u * 4 + 3][r] = av.w;
        Bt[c0 + u * 4 + 0][r] = bv.x; Bt[c0 + u * 4 + 1][r] = bv.y;
        Bt[c0 + u * 4 + 2][r] = bv.z; Bt[c0 + u * 4 + 3][r] = bv.w;
    }
    __syncthreads();
    const int tx = t & 15, ty = t >> 4;
    float acc[4][4] = {};
    #pragma unroll 8
    for (int d = 0; d < 64; ++d) {
        float4 avv = *(const float4*)(&At[d][ty * 4]);
        float4 bvv = *(const float4*)(&Bt[d][tx * 4]);
        const float* av = reinterpret_cast<const float*>(&avv);
        const float* bv = reinterpret_cast<const float*>(&bvv);
        #pragma unroll
        for (int i = 0; i < 4; ++i)
            #pragma unroll
            for (int j = 0; j < 4; ++j)
                acc[i][j] = fmaf(av[i], bv[j], acc[i][j]);
    }
    #pragma unroll
    for (int i = 0; i < 4; ++i) {
        const int ig = it * 64 + ty * 4 + i;
        float4 ov;
        #pragma unroll
        for (int j = 0; j < 4; ++j) {
            const int jg = jt * 64 + tx * 4 + j;
            float val = acc[i][j] * SCALE + mask[b * S_ + jg];
            if (do_sig) val = sigm(val);
            ((float*)&ov)[j] = val;
        }
        *(float4*)(&Om[(size_t)ig * S_ + jt * 64 + tx * 4]) = ov;
    }
}

// ---------------------------------------------------------------------------
// Per-row softmax over raw scores (in place in attn region), then
// quasi = lam * qs, new = attn + quasi. One block per (b,h,i) row.
// ---------------------------------------------------------------------------
__global__ __launch_bounds__(256) void softmax_merge(
    float* __restrict__ attn, float* __restrict__ newp, float* __restrict__ quasi,
    const float* __restrict__ qs, const float* __restrict__ lam)
{
    __shared__ float red[256];
    const int row = blockIdx.x;      // (b*H+h)*S + i
    const int t   = threadIdx.x;
    const int i   = row & (S_ - 1);
    const int bh  = row >> 10;
    const int b   = bh >> 4;
    float* arow = attn + (size_t)row * S_;
    float4 x = *(const float4*)(arow + t * 4);
    float m = fmaxf(fmaxf(x.x, x.y), fmaxf(x.z, x.w));
    red[t] = m; __syncthreads();
    for (int s = 128; s > 0; s >>= 1) {
        if (t < s) red[t] = fmaxf(red[t], red[t + s]);
        __syncthreads();
    }
    m = red[0]; __syncthreads();
    float4 e;
    e.x = __expf(x.x - m); e.y = __expf(x.y - m);
    e.z = __expf(x.z - m); e.w = __expf(x.w - m);
    red[t] = e.x + e.y + e.z + e.w; __syncthreads();
    for (int s = 128; s > 0; s >>= 1) {
        if (t < s) red[t] += red[t + s];
        __syncthreads();
    }
    const float inv = 1.0f / red[0];
    float4 p; p.x = e.x * inv; p.y = e.y * inv; p.z = e.z * inv; p.w = e.w * inv;
    *(float4*)(arow + t * 4) = p;

    const float l = lam[row];
    float4 qv = *(const float4*)(qs + ((size_t)b * S_ + i) * S_ + t * 4);
    float4 qp; qp.x = l * qv.x; qp.y = l * qv.y; qp.z = l * qv.z; qp.w = l * qv.w;
    float4 nv; nv.x = p.x + qp.x; nv.y = p.y + qp.y; nv.z = p.z + qp.z; nv.w = p.w + qp.w;
    *(float4*)(quasi + (size_t)row * S_ + t * 4) = qp;
    *(float4*)(newp  + (size_t)row * S_ + t * 4) = nv;
}

// ---------------------------------------------------------------------------
// ctx[b,s,h*64+d] = sum_k newp[bh,s,k] * v[bh,k,d]. grid (16 m-tiles, 64 bh)
// ---------------------------------------------------------------------------
__global__ __launch_bounds__(256) void gemm_ctx(
    const float* __restrict__ P, const float* __restrict__ Vm, float* __restrict__ ctx)
{
    __shared__ float At[32][64];
    __shared__ float Bs[32][64];
    const int by = blockIdx.x;   // 0..15
    const int bh = blockIdx.y;   // 0..63
    const float* Ap = P  + (size_t)bh * S_ * S_;
    const float* Bp = Vm + (size_t)bh * S_ * DH_;
    const int t = threadIdx.x;
    const int tx = t & 15, ty = t >> 4;
    const int ar = t >> 3, ac = (t & 7) << 2;
    const int br = t >> 4, bc = (t & 15) << 2;

    float acc[4][4] = {};
    for (int k0 = 0; k0 < S_; k0 += 32) {
        float4 a0 = *(const float4*)(Ap + (size_t)(by * 64 + ar) * S_ + k0 + ac);
        float4 a1 = *(const float4*)(Ap + (size_t)(by * 64 + ar + 32) * S_ + k0 + ac);
        float4 b0 = *(const float4*)(Bp + (size_t)(k0 + br) * DH_ + bc);
        float4 b1 = *(const float4*)(Bp + (size_t)(k0 + br + 16) * DH_ + bc);
        At[ac + 0][ar] = a0.x; At[ac + 1][ar] = a0.y;
        At[ac + 2][ar] = a0.z; At[ac + 3][ar] = a0.w;
        At[ac + 0][ar + 32] = a1.x; At[ac + 1][ar + 32] = a1.y;
        At[ac + 2][ar + 32] = a1.z; At[ac + 3][ar + 32] = a1.w;
        *(float4*)(&Bs[br][bc])      = b0;
        *(float4*)(&Bs[br + 16][bc]) = b1;
        __syncthreads();
        #pragma unroll
        for (int kk = 0; kk < 32; ++kk) {
            float4 avv = *(const float4*)(&At[kk][ty * 4]);
            float4 bvv = *(const float4*)(&Bs[kk][tx * 4]);
            const float* av = reinterpret_cast<const float*>(&avv);
            const float* bv = reinterpret_cast<const float*>(&bvv);
            #pragma unroll
            for (int i = 0; i < 4; ++i)
                #pragma unroll
                for (int j = 0; j < 4; ++j)
                    acc[i][j] = fmaf(av[i], bv[j], acc[i][j]);
        }
        __syncthreads();
    }
    const int b = bh >> 4, h = bh & 15;
    #pragma unroll
    for (int i = 0; i < 4; ++i) {
        const int srow = by * 64 + ty * 4 + i;
        float4 ov;
        ((float*)&ov)[0] = acc[i][0]; ((float*)&ov)[1] = acc[i][1];
        ((float*)&ov)[2] = acc[i][2]; ((float*)&ov)[3] = acc[i][3];
        *(float4*)(ctx + ((size_t)b * S_ + srow) * D_ + h * DH_ + tx * 4) = ov;
    }
}

extern "C" void kernel_launch(void* const* d_in, const int* in_sizes, int n_in,
                              void* d_out, int out_size, void* d_ws, size_t ws_size,
                              hipStream_t stream) {
    const float* hs   = (const float*)d_in[0];
    const float* mask = (const float*)d_in[1];
    const float* ce   = (const float*)d_in[2];
    const float* Wq   = (const float*)d_in[3];
    const float* bq   = (const float*)d_in[4];
    const float* Wk   = (const float*)d_in[5];
    const float* bk   = (const float*)d_in[6];
    const float* Wv   = (const float*)d_in[7];
    const float* bv   = (const float*)d_in[8];
    const float* Wcq  = (const float*)d_in[9];
    const float* bcq  = (const float*)d_in[10];
    const float* Wck  = (const float*)d_in[11];
    const float* bck  = (const float*)d_in[12];
    const float* wlqc = (const float*)d_in[13];
    const float* wlqq = (const float*)d_in[14];
    const float* wlkc = (const float*)d_in[15];
    const float* wlkk = (const float*)d_in[16];

    float* out   = (float*)d_out;
    float* ctx   = out;                                   // [B,S,D]
    float* newp  = ctx  + (size_t)B_ * S_ * D_;           // [B,H,S,S]
    float* attn  = newp + (size_t)B_ * H_ * S_ * S_;      // [B,H,S,S]
    float* quasi = attn + (size_t)B_ * H_ * S_ * S_;      // [B,H,S,S]

    float* ws = (float*)d_ws;
    float* q  = ws;                                       // [B,H,S,DH]
    float* k  = q  + (size_t)B_ * H_ * S_ * DH_;
    float* v  = k  + (size_t)B_ * H_ * S_ * DH_;
    float* cq = v  + (size_t)B_ * H_ * S_ * DH_;          // [B,S,DH]
    float* ck = cq + (size_t)B_ * S_ * DH_;
    float* lam = ck + (size_t)B_ * S_ * DH_;              // [B,H,S]
    float* qs  = lam + (size_t)B_ * H_ * S_;              // [B,S,S]

    gemm_qkv<<<dim3(48, 64), 256, 0, stream>>>(hs, Wq, bq, Wk, bk, Wv, bv, q, k, v);
    gemm_cqck<<<dim3(2, 64), 256, 0, stream>>>(ce, Wcq, bcq, Wck, bck, cq, ck);
    lambda_kernel<<<256, 256, 0, stream>>>(q, k, cq, ck, wlqc, wlqq, wlkc, wlkk, lam);
    // quasi scores (head-invariant, computed once): sigmoid((cq.ck)*scale+mask)
    score64<<<dim3(16, 16, 4), 256, 0, stream>>>(cq, ck, qs, mask, 0, 1);
    // raw attention scores -> attn output region (scratch before softmax)
    score64<<<dim3(16, 16, 64), 256, 0, stream>>>(q, k, attn, mask, 4, 0);
    softmax_merge<<<65536, 256, 0, stream>>>(attn, newp, quasi, qs, lam);
    gemm_ctx<<<dim3(16, 64), 256, 0, stream>>>(newp, v, ctx);
}